// Round 1
// baseline (2141.017 us; speedup 1.0000x reference)
//
#include <hip/hip_runtime.h>
#include <math.h>

#define HD 1024   // hidden
#define FD 4096   // ffn
#define NE 8      // experts
#define NT 2048   // tokens (B*S)

// ---------------- ws layout ----------------
// [0,32)                counts[8] (int)
// [1024, 1024+65536)    lists[E][T] (int)  pair id p = t*2+k
// [66560, 66560+16384)  route_w[T*2] (float)
// [82944, +67108864)    hmid[T*2][F] (float)
#define WS_LISTS   1024
#define WS_ROUTEW  (1024 + NE*NT*4)
#define WS_HMID    (1024 + NE*NT*4 + NT*2*4)

__global__ void zero_out_kernel(float* __restrict__ out, int n, int* __restrict__ counts) {
    int i = blockIdx.x * blockDim.x + threadIdx.x;
    if (i < NE) counts[i] = 0;
    int stride = gridDim.x * blockDim.x;
    for (int j = i; j < n; j += stride) out[j] = 0.f;
}

__global__ __launch_bounds__(128)
void router_kernel(const float* __restrict__ x, const float* __restrict__ Wr,
                   int* __restrict__ counts, int* __restrict__ lists,
                   float* __restrict__ route_w) {
    int t = blockIdx.x;
    int tid = threadIdx.x;
    float acc[NE];
#pragma unroll
    for (int e = 0; e < NE; e++) acc[e] = 0.f;
    const float* xt = x + (size_t)t * HD;
    for (int h = tid; h < HD; h += 128) {
        float xv = xt[h];
#pragma unroll
        for (int e = 0; e < NE; e++) acc[e] += xv * Wr[e * HD + h];
    }
    __shared__ float red[NE][128];
#pragma unroll
    for (int e = 0; e < NE; e++) red[e][tid] = acc[e];
    __syncthreads();
    for (int s = 64; s > 0; s >>= 1) {
        if (tid < s) {
#pragma unroll
            for (int e = 0; e < NE; e++) red[e][tid] += red[e][tid + s];
        }
        __syncthreads();
    }
    if (tid == 0) {
        // top-2 by logit (monotonic with softmax prob); ties -> lowest index, matching top_k
        int i0 = 0; float l0 = red[0][0];
        for (int e = 1; e < NE; e++) { float v = red[e][0]; if (v > l0) { l0 = v; i0 = e; } }
        int i1 = -1; float l1 = -3.0e38f;
        for (int e = 0; e < NE; e++) {
            if (e == i0) continue;
            float v = red[e][0]; if (v > l1) { l1 = v; i1 = e; }
        }
        // renormalized top-2 softmax weights = softmax over the two selected logits
        float w0 = 1.f / (1.f + expf(l1 - l0));
        float w1 = 1.f - w0;
        int s0 = atomicAdd(&counts[i0], 1);
        lists[i0 * NT + s0] = t * 2;
        route_w[t * 2] = w0;
        int s1 = atomicAdd(&counts[i1], 1);
        lists[i1 * NT + s1] = t * 2 + 1;
        route_w[t * 2 + 1] = w1;
    }
}

// GEMM1: for expert e, gathered rows X[tok] @ W1[e] and @ W3[e], SwiGLU fuse -> hmid[p][:]
// BM=64, BN=64, BK=16, 256 threads, 4x4 micro-tile, dual accumulators.
__global__ __launch_bounds__(256)
void gemm1_kernel(const float* __restrict__ x, const float* __restrict__ W1,
                  const float* __restrict__ W3,
                  const int* __restrict__ counts, const int* __restrict__ lists,
                  float* __restrict__ hmid) {
    int e = blockIdx.z;
    int cnt = counts[e];
    int m0 = blockIdx.y * 64;
    if (m0 >= cnt) return;
    int n0 = blockIdx.x * 64;
    const float* W1e = W1 + (size_t)e * HD * FD;
    const float* W3e = W3 + (size_t)e * HD * FD;

    __shared__ float As[64][17];     // +1 pad: breaks stride-16 bank conflict on As[m][k]
    __shared__ float B1s[16][64];
    __shared__ float B3s[16][64];
    __shared__ int rowtok[64];
    __shared__ int rowpair[64];

    int tid = threadIdx.x;
    if (tid < 64) {
        int m = m0 + tid;
        int p = (m < cnt) ? lists[e * NT + m] : lists[e * NT];  // clamp to valid row
        rowpair[tid] = p;
        rowtok[tid] = p >> 1;
    }
    __syncthreads();

    const int tx = tid & 15;   // n micro
    const int ty = tid >> 4;   // m micro
    const int lm = tid >> 2;   // A loader row 0..63
    const int lk = (tid & 3) * 4;
    const int ln = tid & 63;   // B loader col
    const int lkb = tid >> 6;  // B loader k base 0..3

    float accG[4][4] = {{0.f}};
    float accU[4][4] = {{0.f}};

    const float* xrow = x + (size_t)rowtok[lm] * HD;

    for (int h0 = 0; h0 < HD; h0 += 16) {
        float4 av = *(const float4*)(xrow + h0 + lk);
        As[lm][lk + 0] = av.x; As[lm][lk + 1] = av.y;
        As[lm][lk + 2] = av.z; As[lm][lk + 3] = av.w;
#pragma unroll
        for (int j = 0; j < 4; j++) {
            int k = lkb + j * 4;
            B1s[k][ln] = W1e[(size_t)(h0 + k) * FD + n0 + ln];
            B3s[k][ln] = W3e[(size_t)(h0 + k) * FD + n0 + ln];
        }
        __syncthreads();
#pragma unroll
        for (int k = 0; k < 16; k++) {
            float a[4];
#pragma unroll
            for (int i = 0; i < 4; i++) a[i] = As[ty * 4 + i][k];
            float4 b1 = *(const float4*)(&B1s[k][tx * 4]);
            float4 b3 = *(const float4*)(&B3s[k][tx * 4]);
            float b1a[4] = {b1.x, b1.y, b1.z, b1.w};
            float b3a[4] = {b3.x, b3.y, b3.z, b3.w};
#pragma unroll
            for (int i = 0; i < 4; i++) {
#pragma unroll
                for (int j = 0; j < 4; j++) {
                    accG[i][j] += a[i] * b1a[j];
                    accU[i][j] += a[i] * b3a[j];
                }
            }
        }
        __syncthreads();
    }

    // epilogue: hmid = silu(gate) * up
#pragma unroll
    for (int i = 0; i < 4; i++) {
        int mr = ty * 4 + i;
        int m = m0 + mr;
        if (m < cnt) {
            int p = rowpair[mr];
            float* hrow = hmid + (size_t)p * FD + n0;
#pragma unroll
            for (int j = 0; j < 4; j++) {
                float g = accG[i][j];
                float sg = g / (1.f + expf(-g));
                hrow[tx * 4 + j] = sg * accU[i][j];
            }
        }
    }
}

// GEMM2: gathered hmid rows @ W2[e] -> weighted atomicAdd into out
__global__ __launch_bounds__(256)
void gemm2_kernel(const float* __restrict__ hmid, const float* __restrict__ W2,
                  const int* __restrict__ counts, const int* __restrict__ lists,
                  const float* __restrict__ route_w, float* __restrict__ out) {
    int e = blockIdx.z;
    int cnt = counts[e];
    int m0 = blockIdx.y * 64;
    if (m0 >= cnt) return;
    int n0 = blockIdx.x * 64;
    const float* W2e = W2 + (size_t)e * FD * HD;

    __shared__ float As[64][17];
    __shared__ float Bs[16][64];
    __shared__ int rowpair[64];

    int tid = threadIdx.x;
    if (tid < 64) {
        int m = m0 + tid;
        rowpair[tid] = (m < cnt) ? lists[e * NT + m] : lists[e * NT];
    }
    __syncthreads();

    const int tx = tid & 15;
    const int ty = tid >> 4;
    const int lm = tid >> 2;
    const int lk = (tid & 3) * 4;
    const int ln = tid & 63;
    const int lkb = tid >> 6;

    float acc[4][4] = {{0.f}};

    const float* arow = hmid + (size_t)rowpair[lm] * FD;

    for (int f0 = 0; f0 < FD; f0 += 16) {
        float4 av = *(const float4*)(arow + f0 + lk);
        As[lm][lk + 0] = av.x; As[lm][lk + 1] = av.y;
        As[lm][lk + 2] = av.z; As[lm][lk + 3] = av.w;
#pragma unroll
        for (int j = 0; j < 4; j++) {
            int k = lkb + j * 4;
            Bs[k][ln] = W2e[(size_t)(f0 + k) * HD + n0 + ln];
        }
        __syncthreads();
#pragma unroll
        for (int k = 0; k < 16; k++) {
            float a[4];
#pragma unroll
            for (int i = 0; i < 4; i++) a[i] = As[ty * 4 + i][k];
            float4 b = *(const float4*)(&Bs[k][tx * 4]);
            float ba[4] = {b.x, b.y, b.z, b.w};
#pragma unroll
            for (int i = 0; i < 4; i++) {
#pragma unroll
                for (int j = 0; j < 4; j++) acc[i][j] += a[i] * ba[j];
            }
        }
        __syncthreads();
    }

#pragma unroll
    for (int i = 0; i < 4; i++) {
        int mr = ty * 4 + i;
        int m = m0 + mr;
        if (m < cnt) {
            int p = rowpair[mr];
            int tok = p >> 1;
            float w = route_w[p];
            float* orow = out + (size_t)tok * HD + n0;
#pragma unroll
            for (int j = 0; j < 4; j++) {
                atomicAdd(&orow[tx * 4 + j], acc[i][j] * w);
            }
        }
    }
}

extern "C" void kernel_launch(void* const* d_in, const int* in_sizes, int n_in,
                              void* d_out, int out_size, void* d_ws, size_t ws_size,
                              hipStream_t stream) {
    const float* x  = (const float*)d_in[0];  // [T, H]
    const float* Wr = (const float*)d_in[1];  // [E, H]
    const float* W1 = (const float*)d_in[2];  // [E, H, F]
    const float* W2 = (const float*)d_in[3];  // [E, F, H]
    const float* W3 = (const float*)d_in[4];  // [E, H, F]
    float* out = (float*)d_out;               // [T, H]

    char* ws = (char*)d_ws;
    int*   counts  = (int*)(ws);
    int*   lists   = (int*)(ws + WS_LISTS);
    float* route_w = (float*)(ws + WS_ROUTEW);
    float* hmid    = (float*)(ws + WS_HMID);   // needs ~64.1 MiB of ws

    hipLaunchKernelGGL(zero_out_kernel, dim3(2048), dim3(256), 0, stream,
                       out, NT * HD, counts);
    hipLaunchKernelGGL(router_kernel, dim3(NT), dim3(128), 0, stream,
                       x, Wr, counts, lists, route_w);
    hipLaunchKernelGGL(gemm1_kernel, dim3(FD / 64, NT / 64, NE), dim3(256), 0, stream,
                       x, W1, W3, counts, lists, hmid);
    hipLaunchKernelGGL(gemm2_kernel, dim3(HD / 64, NT / 64, NE), dim3(256), 0, stream,
                       hmid, W2, counts, lists, route_w, out);
}

// Round 2
// 731.598 us; speedup vs baseline: 2.9265x; 2.9265x over previous
//
#include <hip/hip_runtime.h>
#include <hip/hip_bf16.h>
#include <math.h>

#define HD 1024   // hidden
#define FD 4096   // ffn
#define NE 8      // experts
#define NT 2048   // tokens (B*S)
#define BM 128
#define BN 128
#define BK 32

// ---------------- ws layout ----------------
#define WS_LISTS   1024
#define WS_ROUTEW  (1024 + NE*NT*4)
#define WS_HMID    (1024 + NE*NT*4 + NT*2*4)   // 82944, 16B-aligned; 32 MiB bf16 hmid

typedef __attribute__((ext_vector_type(8))) short bf16x8;   // 8 bf16 = 4 VGPRs (MFMA A/B frag)
typedef __attribute__((ext_vector_type(4))) float f32x4;    // MFMA C/D frag

static __device__ inline unsigned int pk_bf16(float a, float b) {
    __hip_bfloat162 h = __float22bfloat162_rn(make_float2(a, b));
    return *reinterpret_cast<unsigned int*>(&h);
}

__global__ void zero_out_kernel(float* __restrict__ out, int n, int* __restrict__ counts) {
    int i = blockIdx.x * blockDim.x + threadIdx.x;
    if (i < NE) counts[i] = 0;
    int stride = gridDim.x * blockDim.x;
    for (int j = i; j < n; j += stride) out[j] = 0.f;
}

__global__ __launch_bounds__(128)
void router_kernel(const float* __restrict__ x, const float* __restrict__ Wr,
                   int* __restrict__ counts, int* __restrict__ lists,
                   float* __restrict__ route_w) {
    int t = blockIdx.x;
    int tid = threadIdx.x;
    float acc[NE];
#pragma unroll
    for (int e = 0; e < NE; e++) acc[e] = 0.f;
    const float* xt = x + (size_t)t * HD;
    for (int h = tid; h < HD; h += 128) {
        float xv = xt[h];
#pragma unroll
        for (int e = 0; e < NE; e++) acc[e] += xv * Wr[e * HD + h];
    }
    __shared__ float red[NE][128];
#pragma unroll
    for (int e = 0; e < NE; e++) red[e][tid] = acc[e];
    __syncthreads();
    for (int s = 64; s > 0; s >>= 1) {
        if (tid < s) {
#pragma unroll
            for (int e = 0; e < NE; e++) red[e][tid] += red[e][tid + s];
        }
        __syncthreads();
    }
    if (tid == 0) {
        int i0 = 0; float l0 = red[0][0];
        for (int e = 1; e < NE; e++) { float v = red[e][0]; if (v > l0) { l0 = v; i0 = e; } }
        int i1 = -1; float l1 = -3.0e38f;
        for (int e = 0; e < NE; e++) {
            if (e == i0) continue;
            float v = red[e][0]; if (v > l1) { l1 = v; i1 = e; }
        }
        float w0 = 1.f / (1.f + expf(l1 - l0));
        float w1 = 1.f - w0;
        int s0 = atomicAdd(&counts[i0], 1);
        lists[i0 * NT + s0] = t * 2;
        route_w[t * 2] = w0;
        int s1 = atomicAdd(&counts[i1], 1);
        lists[i1 * NT + s1] = t * 2 + 1;
        route_w[t * 2 + 1] = w1;
    }
}

// GEMM1 (bf16 MFMA): gathered X rows @ W1[e] & W3[e], SwiGLU fuse -> hmid (bf16)
// 128x128 tile, BK=32, 4 waves each 64x64 (4x4 tiles of 16x16x32), dual accumulators.
// LDS layout: A[m][k], B[n][k]; row stride 40 bf16 (80 B = 20 words): uniform-bank b128 frag reads.
__global__ __launch_bounds__(256, 2)
void gemm1_kernel(const float* __restrict__ x, const float* __restrict__ W1,
                  const float* __restrict__ W3,
                  const int* __restrict__ counts, const int* __restrict__ lists,
                  unsigned short* __restrict__ hmid) {
    int e = blockIdx.z;
    int cnt = counts[e];
    int m0 = blockIdx.y * BM;
    if (m0 >= cnt) return;
    int n0 = blockIdx.x * BN;
    const float* W1e = W1 + (size_t)e * HD * FD;
    const float* W3e = W3 + (size_t)e * HD * FD;

    __shared__ __align__(16) unsigned short As[128 * 40];
    __shared__ __align__(16) unsigned short B1s[128 * 40];
    __shared__ __align__(16) unsigned short B3s[128 * 40];
    __shared__ int rp_s[128];
    __shared__ int rt_s[128];

    int tid = threadIdx.x;
    if (tid < 128) {
        int m = m0 + tid;
        int p = (m < cnt) ? lists[e * NT + m] : lists[e * NT];
        rp_s[tid] = p;
        rt_s[tid] = p >> 1;
    }
    __syncthreads();

    // A staging: thread covers rows (tid>>3)+r*32, float4-chunk tid&7
    const int a_kq = tid & 7;
    const int a_mb = tid >> 3;
    const float* xr[4];
#pragma unroll
    for (int r = 0; r < 4; r++)
        xr[r] = x + (size_t)rt_s[a_mb + r * 32] * HD + a_kq * 4;

    // B staging: thread owns column n=tid&127, k-half tid>>7 (16 rows, stride FD)
    const int b_n  = tid & 127;
    const int b_kh = tid >> 7;
    const float* b1p = W1e + (size_t)(b_kh * 16) * FD + n0 + b_n;
    const float* b3p = W3e + (size_t)(b_kh * 16) * FD + n0 + b_n;

    const int wv = tid >> 6;
    const int wr = wv >> 1, wc = wv & 1;
    const int lane = tid & 63;
    const int lm = lane & 15;      // frag row (m or n), also C/D col
    const int lg = lane >> 4;      // k-group (quad)

    f32x4 zf = {0.f, 0.f, 0.f, 0.f};
    f32x4 accG[4][4], accU[4][4];
#pragma unroll
    for (int i = 0; i < 4; i++)
#pragma unroll
        for (int j = 0; j < 4; j++) { accG[i][j] = zf; accU[i][j] = zf; }

    for (int h0 = 0; h0 < HD; h0 += BK) {
        float4 av[4];
#pragma unroll
        for (int r = 0; r < 4; r++) av[r] = *(const float4*)(xr[r] + h0);
        float b1v[16], b3v[16];
#pragma unroll
        for (int rr = 0; rr < 16; rr++) b1v[rr] = b1p[(size_t)(h0 + rr) * FD];
#pragma unroll
        for (int rr = 0; rr < 16; rr++) b3v[rr] = b3p[(size_t)(h0 + rr) * FD];

        __syncthreads();   // prior iteration's fragment reads complete
#pragma unroll
        for (int r = 0; r < 4; r++) {
            uint2 w; w.x = pk_bf16(av[r].x, av[r].y); w.y = pk_bf16(av[r].z, av[r].w);
            *(uint2*)&As[(a_mb + r * 32) * 40 + a_kq * 4] = w;
        }
#pragma unroll
        for (int q = 0; q < 4; q++) {
            uint2 w; w.x = pk_bf16(b1v[q * 4 + 0], b1v[q * 4 + 1]);
            w.y = pk_bf16(b1v[q * 4 + 2], b1v[q * 4 + 3]);
            *(uint2*)&B1s[b_n * 40 + b_kh * 16 + q * 4] = w;
        }
#pragma unroll
        for (int q = 0; q < 4; q++) {
            uint2 w; w.x = pk_bf16(b3v[q * 4 + 0], b3v[q * 4 + 1]);
            w.y = pk_bf16(b3v[q * 4 + 2], b3v[q * 4 + 3]);
            *(uint2*)&B3s[b_n * 40 + b_kh * 16 + q * 4] = w;
        }
        __syncthreads();

        bf16x8 af[4], bf1[4], bf3[4];
#pragma unroll
        for (int i = 0; i < 4; i++)
            af[i] = *(const bf16x8*)&As[(wr * 64 + i * 16 + lm) * 40 + lg * 8];
#pragma unroll
        for (int j = 0; j < 4; j++) {
            bf1[j] = *(const bf16x8*)&B1s[(wc * 64 + j * 16 + lm) * 40 + lg * 8];
            bf3[j] = *(const bf16x8*)&B3s[(wc * 64 + j * 16 + lm) * 40 + lg * 8];
        }
#pragma unroll
        for (int i = 0; i < 4; i++)
#pragma unroll
            for (int j = 0; j < 4; j++) {
                accG[i][j] = __builtin_amdgcn_mfma_f32_16x16x32_bf16(af[i], bf1[j], accG[i][j], 0, 0, 0);
                accU[i][j] = __builtin_amdgcn_mfma_f32_16x16x32_bf16(af[i], bf3[j], accU[i][j], 0, 0, 0);
            }
    }

    // epilogue: silu(gate)*up -> bf16 hmid.  C/D: col=lane&15, row=lg*4+reg
#pragma unroll
    for (int i = 0; i < 4; i++) {
#pragma unroll
        for (int r = 0; r < 4; r++) {
            int ml = wr * 64 + i * 16 + lg * 4 + r;
            int m = m0 + ml;
            if (m < cnt) {
                int p = rp_s[ml];
                unsigned short* hrow = hmid + (size_t)p * FD + n0 + wc * 64 + lm;
#pragma unroll
                for (int j = 0; j < 4; j++) {
                    float g = accG[i][j][r];
                    float u = accU[i][j][r];
                    float v = (g / (1.f + expf(-g))) * u;
                    __hip_bfloat16 hb = __float2bfloat16(v);
                    hrow[j * 16] = *reinterpret_cast<unsigned short*>(&hb);
                }
            }
        }
    }
}

// GEMM2 (bf16 MFMA): gathered hmid rows (already bf16) @ W2[e], split-K=2,
// weighted fp32 atomicAdd into out.
__global__ __launch_bounds__(256, 2)
void gemm2_kernel(const unsigned short* __restrict__ hmid, const float* __restrict__ W2,
                  const int* __restrict__ counts, const int* __restrict__ lists,
                  const float* __restrict__ route_w, float* __restrict__ out) {
    int e = blockIdx.z & 7;
    int ks = blockIdx.z >> 3;
    int cnt = counts[e];
    int m0 = blockIdx.y * BM;
    if (m0 >= cnt) return;
    int n0 = blockIdx.x * BN;
    const float* W2e = W2 + (size_t)e * FD * HD;

    __shared__ __align__(16) unsigned short As[128 * 40];
    __shared__ __align__(16) unsigned short Bs[128 * 40];
    __shared__ int rp_s[128];
    __shared__ float rw_s[128];

    int tid = threadIdx.x;
    if (tid < 128) {
        int m = m0 + tid;
        int p = (m < cnt) ? lists[e * NT + m] : lists[e * NT];
        rp_s[tid] = p;
        rw_s[tid] = route_w[p];
    }
    __syncthreads();

    // A staging: bf16 copy; thread covers rows (tid>>2)+r*64, 8-elem chunk tid&3
    const int a_c = tid & 3;
    const int a_mb = tid >> 2;
    const unsigned short* ar[2];
#pragma unroll
    for (int r = 0; r < 2; r++)
        ar[r] = hmid + (size_t)rp_s[a_mb + r * 64] * FD + a_c * 8;

    const int b_n  = tid & 127;
    const int b_kh = tid >> 7;
    const float* bp = W2e + (size_t)(b_kh * 16) * HD + n0 + b_n;

    const int wv = tid >> 6;
    const int wr = wv >> 1, wc = wv & 1;
    const int lane = tid & 63;
    const int lm = lane & 15;
    const int lg = lane >> 4;

    f32x4 zf = {0.f, 0.f, 0.f, 0.f};
    f32x4 acc[4][4];
#pragma unroll
    for (int i = 0; i < 4; i++)
#pragma unroll
        for (int j = 0; j < 4; j++) acc[i][j] = zf;

    const int f_begin = ks * (FD / 2);
    const int f_end   = f_begin + FD / 2;
    for (int f0 = f_begin; f0 < f_end; f0 += BK) {
        uint4 avv[2];
#pragma unroll
        for (int r = 0; r < 2; r++) avv[r] = *(const uint4*)(ar[r] + f0);
        float bv[16];
#pragma unroll
        for (int rr = 0; rr < 16; rr++) bv[rr] = bp[(size_t)(f0 + rr) * HD];

        __syncthreads();
#pragma unroll
        for (int r = 0; r < 2; r++)
            *(uint4*)&As[(a_mb + r * 64) * 40 + a_c * 8] = avv[r];
#pragma unroll
        for (int q = 0; q < 4; q++) {
            uint2 w; w.x = pk_bf16(bv[q * 4 + 0], bv[q * 4 + 1]);
            w.y = pk_bf16(bv[q * 4 + 2], bv[q * 4 + 3]);
            *(uint2*)&Bs[b_n * 40 + b_kh * 16 + q * 4] = w;
        }
        __syncthreads();

        bf16x8 af[4], bf[4];
#pragma unroll
        for (int i = 0; i < 4; i++)
            af[i] = *(const bf16x8*)&As[(wr * 64 + i * 16 + lm) * 40 + lg * 8];
#pragma unroll
        for (int j = 0; j < 4; j++)
            bf[j] = *(const bf16x8*)&Bs[(wc * 64 + j * 16 + lm) * 40 + lg * 8];
#pragma unroll
        for (int i = 0; i < 4; i++)
#pragma unroll
            for (int j = 0; j < 4; j++)
                acc[i][j] = __builtin_amdgcn_mfma_f32_16x16x32_bf16(af[i], bf[j], acc[i][j], 0, 0, 0);
    }

#pragma unroll
    for (int i = 0; i < 4; i++) {
#pragma unroll
        for (int r = 0; r < 4; r++) {
            int ml = wr * 64 + i * 16 + lg * 4 + r;
            int m = m0 + ml;
            if (m < cnt) {
                int p = rp_s[ml];
                float w = rw_s[ml];
                int tok = p >> 1;
                float* orow = out + (size_t)tok * HD + n0 + wc * 64 + lm;
#pragma unroll
                for (int j = 0; j < 4; j++)
                    atomicAdd(&orow[j * 16], acc[i][j][r] * w);
            }
        }
    }
}

extern "C" void kernel_launch(void* const* d_in, const int* in_sizes, int n_in,
                              void* d_out, int out_size, void* d_ws, size_t ws_size,
                              hipStream_t stream) {
    const float* x  = (const float*)d_in[0];  // [T, H]
    const float* Wr = (const float*)d_in[1];  // [E, H]
    const float* W1 = (const float*)d_in[2];  // [E, H, F]
    const float* W2 = (const float*)d_in[3];  // [E, F, H]
    const float* W3 = (const float*)d_in[4];  // [E, H, F]
    float* out = (float*)d_out;               // [T, H]

    char* ws = (char*)d_ws;
    int*   counts  = (int*)(ws);
    int*   lists   = (int*)(ws + WS_LISTS);
    float* route_w = (float*)(ws + WS_ROUTEW);
    unsigned short* hmid = (unsigned short*)(ws + WS_HMID);  // [NT*2][FD] bf16, 32 MiB

    hipLaunchKernelGGL(zero_out_kernel, dim3(2048), dim3(256), 0, stream,
                       out, NT * HD, counts);
    hipLaunchKernelGGL(router_kernel, dim3(NT), dim3(128), 0, stream,
                       x, Wr, counts, lists, route_w);
    hipLaunchKernelGGL(gemm1_kernel, dim3(FD / BN, NT / BM, NE), dim3(256), 0, stream,
                       x, W1, W3, counts, lists, hmid);
    hipLaunchKernelGGL(gemm2_kernel, dim3(HD / BN, NT / BM, NE * 2), dim3(256), 0, stream,
                       hmid, W2, counts, lists, route_w, out);
}

// Round 3
// 666.647 us; speedup vs baseline: 3.2116x; 1.0974x over previous
//
#include <hip/hip_runtime.h>
#include <hip/hip_bf16.h>
#include <math.h>

#define HD 1024   // hidden
#define FD 4096   // ffn
#define NE 8      // experts
#define NT 2048   // tokens (B*S)
#define BM 128
#define BN 128
#define BK 32

// ---------------- ws layout (needs >= 176 MiB) ----------------
// counts @0, lists @1024 (64KB), route_w @66560 (16KB)
// xb    @ 1 MiB  : [NT][HD] bf16           (4 MiB)
// hmid  @ 8 MiB  : [2*NT][FD] bf16         (32 MiB)
// wbuf  @ 48 MiB : conv1: W1b/W3b [16][FD][HD] bf16 (128 MiB)
//                  conv2 (after gemm1): W2b [8][HD][FD] bf16 (64 MiB)
// opair @112 MiB : [2][2*NT][HD] f32       (32 MiB)   (after W2b, no overlap)
#define WS_LISTS   1024
#define WS_ROUTEW  (1024 + NE*NT*4)
#define WS_XB      ((size_t)1 << 20)
#define WS_HMID    ((size_t)8 << 20)
#define WS_WBUF    ((size_t)48 << 20)
#define WS_OPAIR   ((size_t)112 << 20)

typedef __attribute__((ext_vector_type(8))) short bf16x8;   // MFMA A/B frag (4 VGPRs)
typedef __attribute__((ext_vector_type(4))) float f32x4;    // MFMA C/D frag

static __device__ __forceinline__ unsigned int pk_bf16(float a, float b) {
    __hip_bfloat162 h = __float22bfloat162_rn(make_float2(a, b));
    return *reinterpret_cast<unsigned int*>(&h);
}

// async 16B/lane global->LDS. LDS dest = l + lane*16 (wave-uniform l required).
static __device__ __forceinline__ void gll16(const void* g, void* l) {
    __builtin_amdgcn_global_load_lds(
        (const __attribute__((address_space(1))) unsigned int*)g,
        (__attribute__((address_space(3))) unsigned int*)l,
        16, 0, 0);
}

__global__ void prep_kernel(const float* __restrict__ x, unsigned short* __restrict__ xb,
                            int* __restrict__ counts) {
    int idx = blockIdx.x * 256 + threadIdx.x;   // 524288 threads: 4 floats each
    if (idx < NE) counts[idx] = 0;
    float4 v = *(const float4*)(x + (size_t)idx * 4);
    *(uint2*)(xb + (size_t)idx * 4) = make_uint2(pk_bf16(v.x, v.y), pk_bf16(v.z, v.w));
}

__global__ __launch_bounds__(128)
void router_kernel(const float* __restrict__ x, const float* __restrict__ Wr,
                   int* __restrict__ counts, int* __restrict__ lists,
                   float* __restrict__ route_w) {
    int t = blockIdx.x;
    int tid = threadIdx.x;
    float acc[NE];
#pragma unroll
    for (int e = 0; e < NE; e++) acc[e] = 0.f;
    const float* xt = x + (size_t)t * HD;
    for (int h = tid; h < HD; h += 128) {
        float xv = xt[h];
#pragma unroll
        for (int e = 0; e < NE; e++) acc[e] += xv * Wr[e * HD + h];
    }
    __shared__ float red[NE][128];
#pragma unroll
    for (int e = 0; e < NE; e++) red[e][tid] = acc[e];
    __syncthreads();
    for (int s = 64; s > 0; s >>= 1) {
        if (tid < s) {
#pragma unroll
            for (int e = 0; e < NE; e++) red[e][tid] += red[e][tid + s];
        }
        __syncthreads();
    }
    if (tid == 0) {
        int i0 = 0; float l0 = red[0][0];
        for (int e = 1; e < NE; e++) { float v = red[e][0]; if (v > l0) { l0 = v; i0 = e; } }
        int i1 = -1; float l1 = -3.0e38f;
        for (int e = 0; e < NE; e++) {
            if (e == i0) continue;
            float v = red[e][0]; if (v > l1) { l1 = v; i1 = e; }
        }
        float w0 = 1.f / (1.f + expf(l1 - l0));
        float w1 = 1.f - w0;
        int s0 = atomicAdd(&counts[i0], 1);
        lists[i0 * NT + s0] = t * 2;
        route_w[t * 2] = w0;
        int s1 = atomicAdd(&counts[i1], 1);
        lists[i1 * NT + s1] = t * 2 + 1;
        route_w[t * 2 + 1] = w1;
    }
}

// Transpose+convert: src fp32 [R][C] -> dst bf16 [C][R]. z selects slice:
// z<8 -> srcA + z*R*C, else srcB + (z-8)*R*C; dst + z*R*C.
__global__ __launch_bounds__(256)
void transp_kernel(const float* __restrict__ srcA, const float* __restrict__ srcB,
                   unsigned short* __restrict__ dst, int R, int C) {
    __shared__ float tile[64][65];
    int z = blockIdx.z;
    const float* src = (z < 8) ? (srcA + (size_t)z * R * C) : (srcB + (size_t)(z - 8) * R * C);
    unsigned short* d = dst + (size_t)z * R * C;
    int c0 = blockIdx.x * 64, r0 = blockIdx.y * 64;
    int t = threadIdx.x;
    int rr = t >> 4, cc = (t & 15) * 4;
#pragma unroll
    for (int i = 0; i < 4; i++) {
        int r = rr + i * 16;
        float4 v = *(const float4*)(src + (size_t)(r0 + r) * C + c0 + cc);
        tile[cc + 0][r] = v.x; tile[cc + 1][r] = v.y;
        tile[cc + 2][r] = v.z; tile[cc + 3][r] = v.w;
    }
    __syncthreads();
    int cl = t >> 2, rc = (t & 3) * 16;
    unsigned int o[8];
#pragma unroll
    for (int i = 0; i < 8; i++)
        o[i] = pk_bf16(tile[cl][rc + 2 * i], tile[cl][rc + 2 * i + 1]);
    unsigned short* dp = d + (size_t)(c0 + cl) * R + r0 + rc;
    *(uint4*)(dp)     = make_uint4(o[0], o[1], o[2], o[3]);
    *(uint4*)(dp + 8) = make_uint4(o[4], o[5], o[6], o[7]);
}

// GEMM1: gathered xb rows @ W1b/W3b (both [n][k] bf16), SwiGLU -> hmid bf16.
// 128x128x32 tile, 4 waves x (64x64), global_load_lds staging, XCD-grouped grid.
__global__ __launch_bounds__(256, 2)
void gemm1_kernel(const unsigned short* __restrict__ xb, const unsigned short* __restrict__ wbuf,
                  const int* __restrict__ counts, const int* __restrict__ lists,
                  unsigned short* __restrict__ hmid) {
    int xcd = blockIdx.x;                 // 0..7
    int y = blockIdx.y;                   // 0..511
    int en = xcd + 8 * (y >> 4);          // 0..255: (e, nblk) group — same-xcd m-neighbors
    int mblk = y & 15;
    int e = en >> 5;
    int nblk = en & 31;
    int cnt = counts[e];
    int m0 = mblk * BM;
    if (m0 >= cnt) return;
    int n0 = nblk * BN;
    const unsigned short* W1b = wbuf + (size_t)e * FD * HD;
    const unsigned short* W3b = wbuf + (size_t)(8 + e) * FD * HD;

    __shared__ __align__(16) unsigned short As[128 * 32];
    __shared__ __align__(16) unsigned short B1s[128 * 32];
    __shared__ __align__(16) unsigned short B3s[128 * 32];
    __shared__ int rp_s[128];

    int tid = threadIdx.x;
    if (tid < 128) {
        int m = m0 + tid;
        rp_s[tid] = (m < cnt) ? lists[e * NT + m] : lists[e * NT];
    }
    __syncthreads();

    const int w = tid >> 6;
    const int lane = tid & 63;
    const int srow = lane >> 2;     // 0..15 row within 16-row issue
    const int schunk = lane & 3;    // 16B chunk within 64B row

    const unsigned short *gA[2], *gB1[2], *gB3[2];
    unsigned short *lA[2], *lB1[2], *lB3[2];
#pragma unroll
    for (int q = 0; q < 2; q++) {
        int row = w * 32 + q * 16 + srow;
        gA[q]  = xb  + (size_t)(rp_s[row] >> 1) * HD + schunk * 8;
        gB1[q] = W1b + (size_t)(n0 + row) * HD + schunk * 8;
        gB3[q] = W3b + (size_t)(n0 + row) * HD + schunk * 8;
        lA[q]  = &As [(w * 32 + q * 16) * 32];
        lB1[q] = &B1s[(w * 32 + q * 16) * 32];
        lB3[q] = &B3s[(w * 32 + q * 16) * 32];
    }

    const int wr = w >> 1, wc = w & 1;
    const int lm = lane & 15, lg = lane >> 4;

    f32x4 zf = {0.f, 0.f, 0.f, 0.f};
    f32x4 accG[4][4], accU[4][4];
#pragma unroll
    for (int i = 0; i < 4; i++)
#pragma unroll
        for (int j = 0; j < 4; j++) { accG[i][j] = zf; accU[i][j] = zf; }

    for (int h0 = 0; h0 < HD; h0 += BK) {
        __syncthreads();                    // prior frag reads complete
#pragma unroll
        for (int q = 0; q < 2; q++) {
            gll16(gA[q] + h0, lA[q]);
            gll16(gB1[q] + h0, lB1[q]);
            gll16(gB3[q] + h0, lB3[q]);
        }
        __syncthreads();                    // vmcnt drain: staging complete

        bf16x8 af[4], b1f[4], b3f[4];
#pragma unroll
        for (int i = 0; i < 4; i++)
            af[i] = *(const bf16x8*)&As[(wr * 64 + i * 16 + lm) * 32 + lg * 8];
#pragma unroll
        for (int j = 0; j < 4; j++) {
            b1f[j] = *(const bf16x8*)&B1s[(wc * 64 + j * 16 + lm) * 32 + lg * 8];
            b3f[j] = *(const bf16x8*)&B3s[(wc * 64 + j * 16 + lm) * 32 + lg * 8];
        }
#pragma unroll
        for (int i = 0; i < 4; i++)
#pragma unroll
            for (int j = 0; j < 4; j++) {
                accG[i][j] = __builtin_amdgcn_mfma_f32_16x16x32_bf16(af[i], b1f[j], accG[i][j], 0, 0, 0);
                accU[i][j] = __builtin_amdgcn_mfma_f32_16x16x32_bf16(af[i], b3f[j], accU[i][j], 0, 0, 0);
            }
    }

    // epilogue: silu(gate)*up -> bf16. C/D: col(n)=lane&15, row(m)=lg*4+reg (validated R2)
#pragma unroll
    for (int i = 0; i < 4; i++) {
#pragma unroll
        for (int r = 0; r < 4; r++) {
            int ml = wr * 64 + i * 16 + lg * 4 + r;
            int m = m0 + ml;
            if (m < cnt) {
                int p = rp_s[ml];
                unsigned short* hrow = hmid + (size_t)p * FD + n0 + wc * 64 + lm;
#pragma unroll
                for (int j = 0; j < 4; j++) {
                    float g = accG[i][j][r];
                    float u = accU[i][j][r];
                    float v = (g / (1.f + expf(-g))) * u;
                    __hip_bfloat16 hb = __float2bfloat16(v);
                    hrow[j * 16] = *reinterpret_cast<unsigned short*>(&hb);
                }
            }
        }
    }
}

// GEMM2: gathered hmid rows @ W2b [n=h][k=f] bf16, split-K=2, plain stores to opair.
__global__ __launch_bounds__(256, 2)
void gemm2_kernel(const unsigned short* __restrict__ hmid, const unsigned short* __restrict__ wbuf,
                  const int* __restrict__ counts, const int* __restrict__ lists,
                  float* __restrict__ opair) {
    int xcd = blockIdx.x;                 // 0..7
    int y = blockIdx.y;                   // 0..255
    int grp = xcd + 8 * (y >> 4);         // 0..127 = (ks, e, nblk)
    int mblk = y & 15;
    int ks = grp >> 6;
    int rest = grp & 63;
    int e = rest >> 3;
    int nblk = rest & 7;
    int cnt = counts[e];
    int m0 = mblk * BM;
    if (m0 >= cnt) return;
    int n0 = nblk * BN;
    const unsigned short* W2b = wbuf + (size_t)e * HD * FD;

    __shared__ __align__(16) unsigned short As[128 * 32];
    __shared__ __align__(16) unsigned short Bs[128 * 32];
    __shared__ int rp_s[128];

    int tid = threadIdx.x;
    if (tid < 128) {
        int m = m0 + tid;
        rp_s[tid] = (m < cnt) ? lists[e * NT + m] : lists[e * NT];
    }
    __syncthreads();

    const int w = tid >> 6;
    const int lane = tid & 63;
    const int srow = lane >> 2;
    const int schunk = lane & 3;

    const unsigned short *gA[2], *gB[2];
    unsigned short *lA[2], *lB[2];
#pragma unroll
    for (int q = 0; q < 2; q++) {
        int row = w * 32 + q * 16 + srow;
        gA[q] = hmid + (size_t)rp_s[row] * FD + schunk * 8;
        gB[q] = W2b + (size_t)(n0 + row) * FD + schunk * 8;
        lA[q] = &As[(w * 32 + q * 16) * 32];
        lB[q] = &Bs[(w * 32 + q * 16) * 32];
    }

    const int wr = w >> 1, wc = w & 1;
    const int lm = lane & 15, lg = lane >> 4;

    f32x4 zf = {0.f, 0.f, 0.f, 0.f};
    f32x4 acc[4][4];
#pragma unroll
    for (int i = 0; i < 4; i++)
#pragma unroll
        for (int j = 0; j < 4; j++) acc[i][j] = zf;

    const int f_begin = ks * (FD / 2);
    const int f_end = f_begin + FD / 2;
    for (int f0 = f_begin; f0 < f_end; f0 += BK) {
        __syncthreads();
#pragma unroll
        for (int q = 0; q < 2; q++) {
            gll16(gA[q] + f0, lA[q]);
            gll16(gB[q] + f0, lB[q]);
        }
        __syncthreads();

        bf16x8 af[4], bf[4];
#pragma unroll
        for (int i = 0; i < 4; i++)
            af[i] = *(const bf16x8*)&As[(wr * 64 + i * 16 + lm) * 32 + lg * 8];
#pragma unroll
        for (int j = 0; j < 4; j++)
            bf[j] = *(const bf16x8*)&Bs[(wc * 64 + j * 16 + lm) * 32 + lg * 8];
#pragma unroll
        for (int i = 0; i < 4; i++)
#pragma unroll
            for (int j = 0; j < 4; j++)
                acc[i][j] = __builtin_amdgcn_mfma_f32_16x16x32_bf16(af[i], bf[j], acc[i][j], 0, 0, 0);
    }

#pragma unroll
    for (int i = 0; i < 4; i++) {
#pragma unroll
        for (int r = 0; r < 4; r++) {
            int ml = wr * 64 + i * 16 + lg * 4 + r;
            int m = m0 + ml;
            if (m < cnt) {
                int p = rp_s[ml];
                float* op = opair + ((size_t)ks * (2 * NT) + p) * HD + n0 + wc * 64 + lm;
#pragma unroll
                for (int j = 0; j < 4; j++) op[j * 16] = acc[i][j][r];
            }
        }
    }
}

// out[tok] = w0*(o_ks0[2t]+o_ks1[2t]) + w1*(o_ks0[2t+1]+o_ks1[2t+1])
__global__ __launch_bounds__(256)
void combine_kernel(const float* __restrict__ opair, const float* __restrict__ route_w,
                    float* __restrict__ out) {
    int idx = blockIdx.x * 256 + threadIdx.x;   // 524288
    int tok = idx >> 8;
    int hc = (idx & 255) * 4;
    const float* o0 = opair;
    const float* o1 = opair + (size_t)(2 * NT) * HD;
    size_t r0 = (size_t)(2 * tok) * HD + hc;
    size_t r1 = (size_t)(2 * tok + 1) * HD + hc;
    float w0 = route_w[2 * tok], w1 = route_w[2 * tok + 1];
    float4 a = *(const float4*)(o0 + r0);
    float4 b = *(const float4*)(o1 + r0);
    float4 c = *(const float4*)(o0 + r1);
    float4 d = *(const float4*)(o1 + r1);
    float4 r;
    r.x = w0 * (a.x + b.x) + w1 * (c.x + d.x);
    r.y = w0 * (a.y + b.y) + w1 * (c.y + d.y);
    r.z = w0 * (a.z + b.z) + w1 * (c.z + d.z);
    r.w = w0 * (a.w + b.w) + w1 * (c.w + d.w);
    *(float4*)(out + (size_t)tok * HD + hc) = r;
}

extern "C" void kernel_launch(void* const* d_in, const int* in_sizes, int n_in,
                              void* d_out, int out_size, void* d_ws, size_t ws_size,
                              hipStream_t stream) {
    const float* x  = (const float*)d_in[0];  // [T, H]
    const float* Wr = (const float*)d_in[1];  // [E, H]
    const float* W1 = (const float*)d_in[2];  // [E, H, F]
    const float* W2 = (const float*)d_in[3];  // [E, F, H]
    const float* W3 = (const float*)d_in[4];  // [E, H, F]
    float* out = (float*)d_out;               // [T, H]

    char* ws = (char*)d_ws;
    int*   counts  = (int*)(ws);
    int*   lists   = (int*)(ws + WS_LISTS);
    float* route_w = (float*)(ws + WS_ROUTEW);
    unsigned short* xb   = (unsigned short*)(ws + WS_XB);
    unsigned short* hmid = (unsigned short*)(ws + WS_HMID);
    unsigned short* wbuf = (unsigned short*)(ws + WS_WBUF);
    float* opair = (float*)(ws + WS_OPAIR);

    hipLaunchKernelGGL(prep_kernel, dim3(2048), dim3(256), 0, stream, x, xb, counts);
    hipLaunchKernelGGL(router_kernel, dim3(NT), dim3(128), 0, stream,
                       x, Wr, counts, lists, route_w);
    // W1,W3 [H][F] -> wbuf [16][F][H] bf16
    hipLaunchKernelGGL(transp_kernel, dim3(FD / 64, HD / 64, 16), dim3(256), 0, stream,
                       W1, W3, wbuf, HD, FD);
    hipLaunchKernelGGL(gemm1_kernel, dim3(8, 512), dim3(256), 0, stream,
                       xb, wbuf, counts, lists, hmid);
    // W2 [F][H] -> wbuf [8][H][F] bf16 (overwrites W1b region; gemm1 done)
    hipLaunchKernelGGL(transp_kernel, dim3(HD / 64, FD / 64, 8), dim3(256), 0, stream,
                       W2, W2, wbuf, FD, HD);
    hipLaunchKernelGGL(gemm2_kernel, dim3(8, 256), dim3(256), 0, stream,
                       hmid, wbuf, counts, lists, opair);
    hipLaunchKernelGGL(combine_kernel, dim3(2048), dim3(256), 0, stream,
                       opair, route_w, out);
}